// Round 2
// baseline (67.571 us; speedup 1.0000x reference)
//
#include <hip/hip_runtime.h>

// AdjacencySmoothnessLoss: out = 0.1 * sum |a[i][j] - 0.25*(a[i-1][j]+a[i+1][j]+a[i][j-1]+a[i][j+1])|
// over interior i,j in [1, 8190]. a is 8192x8192 fp32.
//
// Single fused kernel: column-chunked float4 stream, register row rotation,
// 2-row unroll (2 loads in flight/wave), per-block atomicAdd of scaled partial.

#define N 8192
#define ROWS_PER_BLOCK 128      // halo overhead 2/128 = 1.6%
#define TPB 256
#define COL_BLOCKS (N / (4 * TPB))                                  // 8
#define ROW_BLOCKS ((N - 2 + ROWS_PER_BLOCK - 1) / ROWS_PER_BLOCK)  // 64 -> 512 blocks = 2/CU

__global__ __launch_bounds__(TPB) void smooth_fused(const float* __restrict__ a,
                                                    float* __restrict__ out) {
    const int tid  = threadIdx.x;
    const int lane = tid & 63;
    const int c0   = (blockIdx.x * TPB + tid) * 4;   // aligned float4 chunk start col
    const int r0   = 1 + blockIdx.y * ROWS_PER_BLOCK;
    const int r1   = min(r0 + ROWS_PER_BLOCK - 1, N - 2);
    // every block has an EVEN number of rows (128, last block 126) -> 2-row unroll safe

    const float* base = a + c0;
    float4 p = *(const float4*)(base + (size_t)(r0 - 1) * N);   // row r-1
    float4 c = *(const float4*)(base + (size_t)r0 * N);         // row r

    float acc = 0.0f;

    for (int r = r0; r <= r1; r += 2) {
        // two loads in flight before any use
        float4 n1 = *(const float4*)(base + (size_t)(r + 1) * N);
        float4 n2 = *(const float4*)(base + (size_t)(r + 2) * N);

        // ---- row r: vertical = p, n1; center = c ----
        {
            float left  = __shfl_up(c.w, 1);
            float right = __shfl_down(c.x, 1);
            if (lane == 0  && c0 > 0)     left  = a[(size_t)r * N + c0 - 1];
            if (lane == 63 && c0 + 4 < N) right = a[(size_t)r * N + c0 + 4];
            if (c0 >= 1)
                acc += fabsf(c.x - 0.25f * (p.x + n1.x + left + c.y));
            acc += fabsf(c.y - 0.25f * (p.y + n1.y + c.x + c.z));
            acc += fabsf(c.z - 0.25f * (p.z + n1.z + c.y + c.w));
            if (c0 + 3 <= N - 2)
                acc += fabsf(c.w - 0.25f * (p.w + n1.w + c.z + right));
        }
        // ---- row r+1: vertical = c, n2; center = n1 ----
        {
            float left  = __shfl_up(n1.w, 1);
            float right = __shfl_down(n1.x, 1);
            if (lane == 0  && c0 > 0)     left  = a[(size_t)(r + 1) * N + c0 - 1];
            if (lane == 63 && c0 + 4 < N) right = a[(size_t)(r + 1) * N + c0 + 4];
            if (c0 >= 1)
                acc += fabsf(n1.x - 0.25f * (c.x + n2.x + left + n1.y));
            acc += fabsf(n1.y - 0.25f * (c.y + n2.y + n1.x + n1.z));
            acc += fabsf(n1.z - 0.25f * (c.z + n2.z + n1.y + n1.w));
            if (c0 + 3 <= N - 2)
                acc += fabsf(n1.w - 0.25f * (c.w + n2.w + n1.z + right));
        }

        p = n1;
        c = n2;
    }

    // wave64 shuffle reduce
    for (int off = 32; off; off >>= 1) acc += __shfl_down(acc, off);

    __shared__ float wsum[TPB / 64];
    if (lane == 0) wsum[tid >> 6] = acc;
    __syncthreads();
    if (tid == 0) {
        float s = 0.0f;
        #pragma unroll
        for (int w = 0; w < TPB / 64; ++w) s += wsum[w];
        atomicAdd(out, 0.1f * s);   // 512 atomics total, device scope
    }
}

extern "C" void kernel_launch(void* const* d_in, const int* in_sizes, int n_in,
                              void* d_out, int out_size, void* d_ws, size_t ws_size,
                              hipStream_t stream) {
    const float* a = (const float*)d_in[0];
    float* out     = (float*)d_out;

    // zero the single-float output each call (graph-capturable memset node)
    hipMemsetAsync(out, 0, sizeof(float), stream);

    dim3 grid(COL_BLOCKS, ROW_BLOCKS);
    smooth_fused<<<grid, TPB, 0, stream>>>(a, out);
}

// Round 3
// 54.705 us; speedup vs baseline: 1.2352x; 1.2352x over previous
//
#include <hip/hip_runtime.h>

// AdjacencySmoothnessLoss: out = 0.1 * sum |a[i][j] - 0.25*(a[i-1][j]+a[i+1][j]+a[i][j-1]+a[i][j+1])|
// over interior i,j in [1, 8190]. a is 8192x8192 fp32.
//
// R3 = R1 kernel body (64-row stripes, 1024 blocks = 4/CU = 16 waves/CU, proven 6.2 TB/s)
//      + fused per-block atomicAdd (drops the 1-block reduce kernel's ~4 us).

#define N 8192
#define ROWS_PER_BLOCK 64       // halo 2/64 = 3.1%; 1024 blocks = 4/CU (occupancy carried R1)
#define TPB 256
#define COL_BLOCKS (N / (4 * TPB))                                  // 8
#define ROW_BLOCKS ((N - 2 + ROWS_PER_BLOCK - 1) / ROWS_PER_BLOCK)  // 128

__global__ __launch_bounds__(TPB) void smooth_fused(const float* __restrict__ a,
                                                    float* __restrict__ out) {
    const int tid  = threadIdx.x;
    const int lane = tid & 63;
    const int c0   = (blockIdx.x * TPB + tid) * 4;   // aligned float4 chunk start col
    const int r0   = 1 + blockIdx.y * ROWS_PER_BLOCK;
    const int r1   = min(r0 + ROWS_PER_BLOCK - 1, N - 2);

    // register-rotated rows: p = row r-1, c = row r, n = row r+1
    float4 p = *(const float4*)(a + (size_t)(r0 - 1) * N + c0);
    float4 c = *(const float4*)(a + (size_t)r0 * N + c0);

    float acc = 0.0f;

    for (int r = r0; r <= r1; ++r) {
        float4 n = *(const float4*)(a + (size_t)(r + 1) * N + c0);

        // horizontal neighbors of the chunk via cross-lane shuffle
        float left  = __shfl_up(c.w, 1);    // lane i-1's c.w == a[r][c0-1]
        float right = __shfl_down(c.x, 1);  // lane i+1's c.x == a[r][c0+4]
        if (lane == 0)  left  = (c0 > 0)      ? a[(size_t)r * N + c0 - 1] : 0.0f;
        if (lane == 63) right = (c0 + 4 < N)  ? a[(size_t)r * N + c0 + 4] : 0.0f;

        if (c0 >= 1)
            acc += fabsf(c.x - 0.25f * (p.x + n.x + left + c.y));
        acc += fabsf(c.y - 0.25f * (p.y + n.y + c.x + c.z));
        acc += fabsf(c.z - 0.25f * (p.z + n.z + c.y + c.w));
        if (c0 + 3 <= N - 2)
            acc += fabsf(c.w - 0.25f * (p.w + n.w + c.z + right));

        p = c;
        c = n;
    }

    // wave64 shuffle reduce
    for (int off = 32; off; off >>= 1) acc += __shfl_down(acc, off);

    __shared__ float wsum[TPB / 64];
    if (lane == 0) wsum[tid >> 6] = acc;
    __syncthreads();
    if (tid == 0) {
        float s = 0.0f;
        #pragma unroll
        for (int w = 0; w < TPB / 64; ++w) s += wsum[w];
        atomicAdd(out, 0.1f * s);   // 1024 atomics total, one address, device scope
    }
}

extern "C" void kernel_launch(void* const* d_in, const int* in_sizes, int n_in,
                              void* d_out, int out_size, void* d_ws, size_t ws_size,
                              hipStream_t stream) {
    const float* a = (const float*)d_in[0];
    float* out     = (float*)d_out;

    // zero the single-float output each call (graph-capturable memset node)
    hipMemsetAsync(out, 0, sizeof(float), stream);

    dim3 grid(COL_BLOCKS, ROW_BLOCKS);
    smooth_fused<<<grid, TPB, 0, stream>>>(a, out);
}

// Round 4
// 48.970 us; speedup vs baseline: 1.3799x; 1.1171x over previous
//
#include <hip/hip_runtime.h>

// AdjacencySmoothnessLoss: out = 0.1 * sum |a[i][j] - 0.25*(a[i-1][j]+a[i+1][j]+a[i][j-1]+a[i][j+1])|
// over interior i,j in [1, 8190]. a is 8192x8192 fp32.
//
// R4 = R1's proven two-kernel structure (fused variants measured SLOWER: memset
// node + same-address atomic burst each cost ~3 us — R2/R3 post-mortems).
// 64-row stripes, 1024 blocks = 4/CU = 16 waves/CU, float4 streaming at
// ~6.2 TB/s (97% of achievable read BW). Added: #pragma unroll 4 for >=4
// loads in flight/wave; reduce_final shrunk to a single wave.

#define N 8192
#define ROWS_PER_BLOCK 64       // halo 2/64 = 3.1%; 1024 blocks = exactly 4/CU
#define TPB 256
#define COL_BLOCKS (N / (4 * TPB))                                  // 8
#define ROW_BLOCKS ((N - 2 + ROWS_PER_BLOCK - 1) / ROWS_PER_BLOCK)  // 128
#define NUM_PARTIALS (COL_BLOCKS * ROW_BLOCKS)                      // 1024

__global__ __launch_bounds__(TPB) void smooth_partial(const float* __restrict__ a,
                                                      float* __restrict__ partial) {
    const int tid  = threadIdx.x;
    const int lane = tid & 63;
    const int c0   = (blockIdx.x * TPB + tid) * 4;   // aligned float4 chunk start col
    const int r0   = 1 + blockIdx.y * ROWS_PER_BLOCK;
    const int r1   = min(r0 + ROWS_PER_BLOCK - 1, N - 2);

    // register-rotated rows: p = row r-1, c = row r, n = row r+1
    float4 p = *(const float4*)(a + (size_t)(r0 - 1) * N + c0);
    float4 c = *(const float4*)(a + (size_t)r0 * N + c0);

    float acc = 0.0f;

    #pragma unroll 4
    for (int r = r0; r <= r1; ++r) {
        float4 n = *(const float4*)(a + (size_t)(r + 1) * N + c0);

        // horizontal neighbors of the chunk via cross-lane shuffle
        float left  = __shfl_up(c.w, 1);    // lane i-1's c.w == a[r][c0-1]
        float right = __shfl_down(c.x, 1);  // lane i+1's c.x == a[r][c0+4]
        if (lane == 0)  left  = (c0 > 0)      ? a[(size_t)r * N + c0 - 1] : 0.0f;
        if (lane == 63) right = (c0 + 4 < N)  ? a[(size_t)r * N + c0 + 4] : 0.0f;

        if (c0 >= 1)
            acc += fabsf(c.x - 0.25f * (p.x + n.x + left + c.y));
        acc += fabsf(c.y - 0.25f * (p.y + n.y + c.x + c.z));
        acc += fabsf(c.z - 0.25f * (p.z + n.z + c.y + c.w));
        if (c0 + 3 <= N - 2)
            acc += fabsf(c.w - 0.25f * (p.w + n.w + c.z + right));

        p = c;
        c = n;
    }

    // wave64 shuffle reduce
    for (int off = 32; off; off >>= 1) acc += __shfl_down(acc, off);

    __shared__ float wsum[TPB / 64];
    if (lane == 0) wsum[tid >> 6] = acc;
    __syncthreads();
    if (tid == 0) {
        float s = 0.0f;
        #pragma unroll
        for (int w = 0; w < TPB / 64; ++w) s += wsum[w];
        partial[blockIdx.y * gridDim.x + blockIdx.x] = s;
    }
}

__global__ __launch_bounds__(64) void reduce_final(const float* __restrict__ partial,
                                                   float* __restrict__ out) {
    // 1024 partials, 64 lanes, 4 float4 per lane
    const int lane = threadIdx.x;
    double s = 0.0;
    #pragma unroll
    for (int i = 0; i < 4; ++i) {
        float4 v = *(const float4*)(partial + (i * 64 + lane) * 4);
        s += (double)v.x + (double)v.y + (double)v.z + (double)v.w;
    }
    // wave64 shuffle reduce on double
    for (int off = 32; off; off >>= 1) s += __shfl_down(s, off);
    if (lane == 0) out[0] = (float)(0.1 * s);
}

extern "C" void kernel_launch(void* const* d_in, const int* in_sizes, int n_in,
                              void* d_out, int out_size, void* d_ws, size_t ws_size,
                              hipStream_t stream) {
    const float* a   = (const float*)d_in[0];
    float* out       = (float*)d_out;
    float* partial   = (float*)d_ws;   // NUM_PARTIALS floats (4 KiB)

    dim3 grid(COL_BLOCKS, ROW_BLOCKS);
    smooth_partial<<<grid, TPB, 0, stream>>>(a, partial);
    reduce_final<<<1, 64, 0, stream>>>(partial, out);
}

// Round 5
// 48.863 us; speedup vs baseline: 1.3829x; 1.0022x over previous
//
#include <hip/hip_runtime.h>

// AdjacencySmoothnessLoss: out = 0.1 * sum |a[i][j] - 0.25*(a[i-1][j]+a[i+1][j]+a[i][j-1]+a[i][j+1])|
// over interior i,j in [1, 8190]. a is 8192x8192 fp32.
//
// R5 = R4 with ROWS_PER_BLOCK 32 (2048 blocks = 8/CU = 32 waves/CU, max
// occupancy) to test latency- vs BW-ceiling-bound. Halo doubles to 6.25% but
// re-reads are L2/L3-absorbed (input ~= L3 capacity, adjacent stripes
// concurrent), so HBM fetch stays ~268 MB. Two-kernel structure is proven
// (fused atomics/memset variants measured slower, R2/R3).

#define N 8192
#define ROWS_PER_BLOCK 32
#define TPB 256
#define COL_BLOCKS (N / (4 * TPB))                                  // 8
#define ROW_BLOCKS ((N - 2 + ROWS_PER_BLOCK - 1) / ROWS_PER_BLOCK)  // 256
#define NUM_PARTIALS (COL_BLOCKS * ROW_BLOCKS)                      // 2048

__global__ __launch_bounds__(TPB) void smooth_partial(const float* __restrict__ a,
                                                      float* __restrict__ partial) {
    const int tid  = threadIdx.x;
    const int lane = tid & 63;
    const int c0   = (blockIdx.x * TPB + tid) * 4;   // aligned float4 chunk start col
    const int r0   = 1 + blockIdx.y * ROWS_PER_BLOCK;
    const int r1   = min(r0 + ROWS_PER_BLOCK - 1, N - 2);

    // register-rotated rows: p = row r-1, c = row r, n = row r+1
    float4 p = *(const float4*)(a + (size_t)(r0 - 1) * N + c0);
    float4 c = *(const float4*)(a + (size_t)r0 * N + c0);

    float acc = 0.0f;

    #pragma unroll 4
    for (int r = r0; r <= r1; ++r) {
        float4 n = *(const float4*)(a + (size_t)(r + 1) * N + c0);

        // horizontal neighbors of the chunk via cross-lane shuffle
        float left  = __shfl_up(c.w, 1);    // lane i-1's c.w == a[r][c0-1]
        float right = __shfl_down(c.x, 1);  // lane i+1's c.x == a[r][c0+4]
        if (lane == 0)  left  = (c0 > 0)      ? a[(size_t)r * N + c0 - 1] : 0.0f;
        if (lane == 63) right = (c0 + 4 < N)  ? a[(size_t)r * N + c0 + 4] : 0.0f;

        if (c0 >= 1)
            acc += fabsf(c.x - 0.25f * (p.x + n.x + left + c.y));
        acc += fabsf(c.y - 0.25f * (p.y + n.y + c.x + c.z));
        acc += fabsf(c.z - 0.25f * (p.z + n.z + c.y + c.w));
        if (c0 + 3 <= N - 2)
            acc += fabsf(c.w - 0.25f * (p.w + n.w + c.z + right));

        p = c;
        c = n;
    }

    // wave64 shuffle reduce
    for (int off = 32; off; off >>= 1) acc += __shfl_down(acc, off);

    __shared__ float wsum[TPB / 64];
    if (lane == 0) wsum[tid >> 6] = acc;
    __syncthreads();
    if (tid == 0) {
        float s = 0.0f;
        #pragma unroll
        for (int w = 0; w < TPB / 64; ++w) s += wsum[w];
        partial[blockIdx.y * gridDim.x + blockIdx.x] = s;
    }
}

__global__ __launch_bounds__(64) void reduce_final(const float* __restrict__ partial,
                                                   float* __restrict__ out) {
    // 2048 partials, 64 lanes, 8 float4 per lane
    const int lane = threadIdx.x;
    double s = 0.0;
    #pragma unroll
    for (int i = 0; i < 8; ++i) {
        float4 v = *(const float4*)(partial + (i * 64 + lane) * 4);
        s += (double)v.x + (double)v.y + (double)v.z + (double)v.w;
    }
    // wave64 shuffle reduce on double
    for (int off = 32; off; off >>= 1) s += __shfl_down(s, off);
    if (lane == 0) out[0] = (float)(0.1 * s);
}

extern "C" void kernel_launch(void* const* d_in, const int* in_sizes, int n_in,
                              void* d_out, int out_size, void* d_ws, size_t ws_size,
                              hipStream_t stream) {
    const float* a   = (const float*)d_in[0];
    float* out       = (float*)d_out;
    float* partial   = (float*)d_ws;   // NUM_PARTIALS floats (8 KiB)

    dim3 grid(COL_BLOCKS, ROW_BLOCKS);
    smooth_partial<<<grid, TPB, 0, stream>>>(a, partial);
    reduce_final<<<1, 64, 0, stream>>>(partial, out);
}